// Round 1
// baseline (175.898 us; speedup 1.0000x reference)
//
#include <hip/hip_runtime.h>
#include <math.h>

#define D 128
#define TWO_D 256
#define S_NEIGH 25
#define NPB 32          // nodes per block in k_main
#define HPAD 260        // padded h row (260%32==4 -> bank-conflict-free float4 reads)

static constexpr float BN_EPS_C = 1e-5f;
static constexpr float NORM_EPS_C = 1e-6f;

// ---------------- K0: transpose W [128][256] -> Wt [256][128]; zero stats ----------------
__global__ void k_prep(const float* __restrict__ W,
                       float* __restrict__ Wt,
                       float* __restrict__ stats) {
    const int k = blockIdx.x;    // 0..255
    const int j = threadIdx.x;   // 0..127
    Wt[k * D + j] = W[j * TWO_D + k];
    if (k < 2) stats[k * D + j] = 0.0f;
}

// ---------------- K1: gather + mean-agg + linear + relu + column stats ----------------
__global__ __launch_bounds__(256, 4) void k_main(
    const float* __restrict__ feat,
    const int* __restrict__ self_idx,
    const int* __restrict__ neigh_idx,
    const float* __restrict__ Wt,
    const float* __restrict__ bias,
    float* __restrict__ out1,     // [N][128] pre-norm output (uses d_out)
    float* __restrict__ stats,    // [0..127]=sum, [128..255]=sumsq
    int N)
{
    __shared__ float h[NPB][HPAD];
    __shared__ float lsum[4][D];
    __shared__ float lsq[4][D];

    const int t = threadIdx.x;
    const int wave = t >> 6;
    const int lane = t & 63;
    const int base = blockIdx.x * NPB;

    // ---- gather phase: each wave gathers 8 nodes; 64 lanes x float2 per row ----
    #pragma unroll
    for (int ni = 0; ni < 8; ++ni) {
        const int n = wave * 8 + ni;
        const int node = base + n;
        float h0 = 0.f, h1 = 0.f, a0 = 0.f, a1 = 0.f;
        if (node < N) {
            const long off = 2 * lane;
            const int si = self_idx[node];
            const float2 fs = *(const float2*)(feat + (long)si * D + off);
            h0 = fs.x; h1 = fs.y;
            const int* nptr = neigh_idx + (long)node * S_NEIGH;
            #pragma unroll 5
            for (int s = 0; s < S_NEIGH; ++s) {
                const int gi = nptr[s];
                const float2 fn = *(const float2*)(feat + (long)gi * D + off);
                a0 += fn.x; a1 += fn.y;
            }
            a0 *= (1.0f / S_NEIGH);
            a1 *= (1.0f / S_NEIGH);
        }
        *(float2*)&h[n][2 * lane]     = make_float2(h0, h1);   // h[0:128] = self
        *(float2*)&h[n][D + 2 * lane] = make_float2(a0, a1);   // h[128:256] = agg
    }
    __syncthreads();

    // ---- GEMM phase: out[n][j] = relu(b[j] + sum_k h[n][k]*Wt[k][j]) ----
    // thread t: cg = t&31 -> cols 4cg..4cg+3 ; slot = t>>5 -> nodes slot*4..slot*4+3
    // 16 FMAs per (1 global float4 + 1 LDS float4) -> VALU-bound, not LDS-bound
    const int cg = t & 31;
    const int slot = t >> 5;
    const float4 b4 = *(const float4*)(bias + 4 * cg);
    float acc[4][4];
    #pragma unroll
    for (int i = 0; i < 4; ++i) {
        acc[i][0] = b4.x; acc[i][1] = b4.y; acc[i][2] = b4.z; acc[i][3] = b4.w;
    }

    for (int k = 0; k < TWO_D; k += 4) {
        const float4 w0 = *(const float4*)(Wt + (long)(k + 0) * D + 4 * cg);
        const float4 w1 = *(const float4*)(Wt + (long)(k + 1) * D + 4 * cg);
        const float4 w2 = *(const float4*)(Wt + (long)(k + 2) * D + 4 * cg);
        const float4 w3 = *(const float4*)(Wt + (long)(k + 3) * D + 4 * cg);
        #pragma unroll
        for (int i = 0; i < 4; ++i) {
            const float4 hv = *(const float4*)&h[slot * 4 + i][k];
            acc[i][0] += hv.x * w0.x + hv.y * w1.x + hv.z * w2.x + hv.w * w3.x;
            acc[i][1] += hv.x * w0.y + hv.y * w1.y + hv.z * w2.y + hv.w * w3.y;
            acc[i][2] += hv.x * w0.z + hv.y * w1.z + hv.z * w2.z + hv.w * w3.z;
            acc[i][3] += hv.x * w0.w + hv.y * w1.w + hv.z * w2.w + hv.w * w3.w;
        }
    }

    // relu + store + per-thread column partials
    float cs[4] = {0.f, 0.f, 0.f, 0.f};
    float cq[4] = {0.f, 0.f, 0.f, 0.f};
    #pragma unroll
    for (int i = 0; i < 4; ++i) {
        const int node = base + slot * 4 + i;
        if (node < N) {
            float4 o;
            o.x = fmaxf(acc[i][0], 0.f);
            o.y = fmaxf(acc[i][1], 0.f);
            o.z = fmaxf(acc[i][2], 0.f);
            o.w = fmaxf(acc[i][3], 0.f);
            *(float4*)(out1 + (long)node * D + 4 * cg) = o;
            cs[0] += o.x;     cs[1] += o.y;     cs[2] += o.z;     cs[3] += o.w;
            cq[0] += o.x*o.x; cq[1] += o.y*o.y; cq[2] += o.z*o.z; cq[3] += o.w*o.w;
        }
    }
    // fold the two slots within each wave (lane ^ 32 has same cg, other slot)
    #pragma unroll
    for (int c = 0; c < 4; ++c) {
        cs[c] += __shfl_xor(cs[c], 32);
        cq[c] += __shfl_xor(cq[c], 32);
    }
    if (lane < 32) {
        *(float4*)&lsum[wave][4 * cg] = make_float4(cs[0], cs[1], cs[2], cs[3]);
        *(float4*)&lsq[wave][4 * cg]  = make_float4(cq[0], cq[1], cq[2], cq[3]);
    }
    __syncthreads();
    if (t < D) {
        atomicAdd(&stats[t], lsum[0][t] + lsum[1][t] + lsum[2][t] + lsum[3][t]);
    } else {
        const int j = t - D;
        atomicAdd(&stats[D + j], lsq[0][j] + lsq[1][j] + lsq[2][j] + lsq[3][j]);
    }
}

// ---------------- K2: batchnorm finalize + row L2 normalize (in-place on d_out) ----------------
__global__ __launch_bounds__(256) void k_final(
    float* __restrict__ out,
    const float* __restrict__ stats,
    const float* __restrict__ gamma,
    const float* __restrict__ beta,
    int N)
{
    __shared__ float scale[D];
    __shared__ float shift[D];
    const int t = threadIdx.x;
    if (t < D) {
        const float invN = 1.0f / (float)N;
        const float mu = stats[t] * invN;
        const float var = stats[D + t] * invN - mu * mu;
        const float sc = gamma[t] * rsqrtf(var + BN_EPS_C);
        scale[t] = sc;
        shift[t] = beta[t] - mu * sc;
    }
    __syncthreads();

    const int row = blockIdx.x * 8 + (t >> 5);
    const int l = t & 31;
    if (row < N) {
        float4 x = *(float4*)(out + (long)row * D + 4 * l);
        const float4 s4 = *(const float4*)&scale[4 * l];
        const float4 f4 = *(const float4*)&shift[4 * l];
        float4 y;
        y.x = x.x * s4.x + f4.x;
        y.y = x.y * s4.y + f4.y;
        y.z = x.z * s4.z + f4.z;
        y.w = x.w * s4.w + f4.w;
        float ss = y.x*y.x + y.y*y.y + y.z*y.z + y.w*y.w;
        #pragma unroll
        for (int m = 16; m >= 1; m >>= 1) ss += __shfl_xor(ss, m);
        const float inv = 1.0f / (sqrtf(ss) + NORM_EPS_C);
        y.x *= inv; y.y *= inv; y.z *= inv; y.w *= inv;
        *(float4*)(out + (long)row * D + 4 * l) = y;
    }
}

extern "C" void kernel_launch(void* const* d_in, const int* in_sizes, int n_in,
                              void* d_out, int out_size, void* d_ws, size_t ws_size,
                              hipStream_t stream) {
    const float* feat      = (const float*)d_in[0];
    const int*   self_idx  = (const int*)d_in[1];
    const int*   neigh_idx = (const int*)d_in[2];
    const float* W         = (const float*)d_in[3];
    const float* b         = (const float*)d_in[4];
    const float* gamma     = (const float*)d_in[5];
    const float* beta      = (const float*)d_in[6];
    float* out = (float*)d_out;
    const int N = in_sizes[1];

    float* Wt    = (float*)d_ws;          // 256*128 floats
    float* stats = Wt + TWO_D * D;        // 256 floats

    k_prep<<<TWO_D, D, 0, stream>>>(W, Wt, stats);
    k_main<<<(N + NPB - 1) / NPB, 256, 0, stream>>>(feat, self_idx, neigh_idx, Wt, b, out, stats, N);
    k_final<<<(N + 7) / 8, 256, 0, stream>>>(out, stats, gamma, beta, N);
}

// Round 2
// 143.390 us; speedup vs baseline: 1.2267x; 1.2267x over previous
//
#include <hip/hip_runtime.h>
#include <math.h>

#define D 128
#define TWO_D 256
#define S_NEIGH 25
#define NPB 32          // nodes per block in k_main
#define HPAD 260        // padded h row (float4-aligned, breaks pow2 stride)

static constexpr float BN_EPS_C = 1e-5f;
static constexpr float NORM_EPS_C = 1e-6f;

// ---------------- K0: transpose W [128][256] -> Wt [256][128]; zero stats ----------------
__global__ void k_prep(const float* __restrict__ W,
                       float* __restrict__ Wt,
                       float* __restrict__ stats) {
    const int k = blockIdx.x;    // 0..255
    const int j = threadIdx.x;   // 0..127
    Wt[k * D + j] = W[j * TWO_D + k];
    if (k < 2) stats[k * D + j] = 0.0f;
}

// ---------------- K1: gather + mean-agg + linear + relu + column stats ----------------
__global__ __launch_bounds__(256, 4) void k_main(
    const float* __restrict__ feat,
    const int* __restrict__ self_idx,
    const int* __restrict__ neigh_idx,
    const float* __restrict__ Wt,
    const float* __restrict__ bias,
    float* __restrict__ out1,     // [N][128] pre-norm output (uses d_out)
    float* __restrict__ stats,    // [0..127]=sum, [128..255]=sumsq
    int N)
{
    __shared__ float h[NPB][HPAD];
    __shared__ int   s_nidx[NPB * S_NEIGH];   // 800 ints
    __shared__ int   s_sidx[NPB];
    __shared__ float lsum[4][D];
    __shared__ float lsq[4][D];

    const int t = threadIdx.x;
    const int wave = t >> 6;
    const int lane = t & 63;
    const int base = blockIdx.x * NPB;
    const int nvalid = min(NPB, N - base);

    // ---- stage indices into LDS: one coalesced sweep ----
    {
        const int V = nvalid * S_NEIGH;             // valid neighbor-index count
        const long goff = (long)base * S_NEIGH;     // 16B-aligned (base*25*4 = blockIdx*3200)
        if (t < (NPB * S_NEIGH) / 4) {              // 200 int4 loaders
            const int e0 = 4 * t;
            if (e0 + 3 < V) {
                ((int4*)s_nidx)[t] = ((const int4*)(neigh_idx + goff))[t];
            } else {
                #pragma unroll
                for (int e = 0; e < 4; ++e)
                    if (e0 + e < V) s_nidx[e0 + e] = neigh_idx[goff + e0 + e];
            }
        } else if (t < (NPB * S_NEIGH) / 4 + NPB) {
            const int i = t - (NPB * S_NEIGH) / 4;
            if (i < nvalid) s_sidx[i] = self_idx[base + i];
        }
    }
    __syncthreads();

    // ---- gather phase: each half-wave (32 lanes x float4) owns one node; 2 nodes/wave in flight ----
    const int sub = lane >> 5;
    const int l32 = lane & 31;
    const int col = 4 * l32;
    #pragma unroll
    for (int ni = 0; ni < 4; ++ni) {
        const int n = wave * 8 + ni * 2 + sub;
        float4 sf = make_float4(0.f, 0.f, 0.f, 0.f);
        float4 a0 = make_float4(0.f, 0.f, 0.f, 0.f);
        float4 a1 = make_float4(0.f, 0.f, 0.f, 0.f);
        if (n < nvalid) {
            sf = *(const float4*)(feat + (long)s_sidx[n] * D + col);
            const int* nid = s_nidx + n * S_NEIGH;
            #pragma unroll
            for (int s = 0; s < S_NEIGH; s += 2) {
                const float4 f = *(const float4*)(feat + (long)nid[s] * D + col);
                a0.x += f.x; a0.y += f.y; a0.z += f.z; a0.w += f.w;
            }
            #pragma unroll
            for (int s = 1; s < S_NEIGH; s += 2) {
                const float4 f = *(const float4*)(feat + (long)nid[s] * D + col);
                a1.x += f.x; a1.y += f.y; a1.z += f.z; a1.w += f.w;
            }
            const float r = 1.0f / S_NEIGH;
            a0.x = (a0.x + a1.x) * r; a0.y = (a0.y + a1.y) * r;
            a0.z = (a0.z + a1.z) * r; a0.w = (a0.w + a1.w) * r;
        }
        *(float4*)&h[n][col]     = sf;   // h[0:128] = self
        *(float4*)&h[n][D + col] = a0;   // h[128:256] = mean-agg
    }
    __syncthreads();

    // ---- GEMM phase: out[n][j] = relu(b[j] + sum_k h[n][k]*Wt[k][j]) ----
    // thread t: cg = t&31 -> cols 4cg..4cg+3 ; slot = t>>5 -> nodes slot*4..slot*4+3
    const int cg = t & 31;
    const int slot = t >> 5;
    const float4 b4 = *(const float4*)(bias + 4 * cg);
    float acc[4][4];
    #pragma unroll
    for (int i = 0; i < 4; ++i) {
        acc[i][0] = b4.x; acc[i][1] = b4.y; acc[i][2] = b4.z; acc[i][3] = b4.w;
    }

    for (int k = 0; k < TWO_D; k += 4) {
        const float4 w0 = *(const float4*)(Wt + (long)(k + 0) * D + 4 * cg);
        const float4 w1 = *(const float4*)(Wt + (long)(k + 1) * D + 4 * cg);
        const float4 w2 = *(const float4*)(Wt + (long)(k + 2) * D + 4 * cg);
        const float4 w3 = *(const float4*)(Wt + (long)(k + 3) * D + 4 * cg);
        #pragma unroll
        for (int i = 0; i < 4; ++i) {
            const float4 hv = *(const float4*)&h[slot * 4 + i][k];
            acc[i][0] += hv.x * w0.x + hv.y * w1.x + hv.z * w2.x + hv.w * w3.x;
            acc[i][1] += hv.x * w0.y + hv.y * w1.y + hv.z * w2.y + hv.w * w3.y;
            acc[i][2] += hv.x * w0.z + hv.y * w1.z + hv.z * w2.z + hv.w * w3.z;
            acc[i][3] += hv.x * w0.w + hv.y * w1.w + hv.z * w2.w + hv.w * w3.w;
        }
    }

    // relu + store + per-thread column partials
    float cs[4] = {0.f, 0.f, 0.f, 0.f};
    float cq[4] = {0.f, 0.f, 0.f, 0.f};
    #pragma unroll
    for (int i = 0; i < 4; ++i) {
        const int node = base + slot * 4 + i;
        if (node < N) {
            float4 o;
            o.x = fmaxf(acc[i][0], 0.f);
            o.y = fmaxf(acc[i][1], 0.f);
            o.z = fmaxf(acc[i][2], 0.f);
            o.w = fmaxf(acc[i][3], 0.f);
            *(float4*)(out1 + (long)node * D + 4 * cg) = o;
            cs[0] += o.x;     cs[1] += o.y;     cs[2] += o.z;     cs[3] += o.w;
            cq[0] += o.x*o.x; cq[1] += o.y*o.y; cq[2] += o.z*o.z; cq[3] += o.w*o.w;
        }
    }
    // fold the two slots within each wave (lane ^ 32 has same cg, other slot)
    #pragma unroll
    for (int c = 0; c < 4; ++c) {
        cs[c] += __shfl_xor(cs[c], 32);
        cq[c] += __shfl_xor(cq[c], 32);
    }
    if (lane < 32) {
        *(float4*)&lsum[wave][4 * cg] = make_float4(cs[0], cs[1], cs[2], cs[3]);
        *(float4*)&lsq[wave][4 * cg]  = make_float4(cq[0], cq[1], cq[2], cq[3]);
    }
    __syncthreads();
    if (t < D) {
        atomicAdd(&stats[t], lsum[0][t] + lsum[1][t] + lsum[2][t] + lsum[3][t]);
    } else {
        const int j = t - D;
        atomicAdd(&stats[D + j], lsq[0][j] + lsq[1][j] + lsq[2][j] + lsq[3][j]);
    }
}

// ---------------- K2: batchnorm finalize + row L2 normalize (in-place on d_out) ----------------
__global__ __launch_bounds__(256) void k_final(
    float* __restrict__ out,
    const float* __restrict__ stats,
    const float* __restrict__ gamma,
    const float* __restrict__ beta,
    int N)
{
    __shared__ float scale[D];
    __shared__ float shift[D];
    const int t = threadIdx.x;
    if (t < D) {
        const float invN = 1.0f / (float)N;
        const float mu = stats[t] * invN;
        const float var = stats[D + t] * invN - mu * mu;
        const float sc = gamma[t] * rsqrtf(var + BN_EPS_C);
        scale[t] = sc;
        shift[t] = beta[t] - mu * sc;
    }
    __syncthreads();

    const int row = blockIdx.x * 8 + (t >> 5);
    const int l = t & 31;
    if (row < N) {
        float4 x = *(float4*)(out + (long)row * D + 4 * l);
        const float4 s4 = *(const float4*)&scale[4 * l];
        const float4 f4 = *(const float4*)&shift[4 * l];
        float4 y;
        y.x = x.x * s4.x + f4.x;
        y.y = x.y * s4.y + f4.y;
        y.z = x.z * s4.z + f4.z;
        y.w = x.w * s4.w + f4.w;
        float ss = y.x*y.x + y.y*y.y + y.z*y.z + y.w*y.w;
        #pragma unroll
        for (int m = 16; m >= 1; m >>= 1) ss += __shfl_xor(ss, m);
        const float inv = 1.0f / (sqrtf(ss) + NORM_EPS_C);
        y.x *= inv; y.y *= inv; y.z *= inv; y.w *= inv;
        *(float4*)(out + (long)row * D + 4 * l) = y;
    }
}

extern "C" void kernel_launch(void* const* d_in, const int* in_sizes, int n_in,
                              void* d_out, int out_size, void* d_ws, size_t ws_size,
                              hipStream_t stream) {
    const float* feat      = (const float*)d_in[0];
    const int*   self_idx  = (const int*)d_in[1];
    const int*   neigh_idx = (const int*)d_in[2];
    const float* W         = (const float*)d_in[3];
    const float* b         = (const float*)d_in[4];
    const float* gamma     = (const float*)d_in[5];
    const float* beta      = (const float*)d_in[6];
    float* out = (float*)d_out;
    const int N = in_sizes[1];

    float* Wt    = (float*)d_ws;          // 256*128 floats
    float* stats = Wt + TWO_D * D;        // 256 floats

    k_prep<<<TWO_D, D, 0, stream>>>(W, Wt, stats);
    k_main<<<(N + NPB - 1) / NPB, 256, 0, stream>>>(feat, self_idx, neigh_idx, Wt, b, out, stats, N);
    k_final<<<(N + 7) / 8, 256, 0, stream>>>(out, stats, gamma, beta, N);
}